// Round 14
// baseline (205.821 us; speedup 1.0000x reference)
//
#include <hip/hip_runtime.h>
#include <stdint.h>

#define S_LEN 2048
#define DMODEL 2048
#define NQH 16
#define NKVH 4
#define HDK 128

typedef __bf16 bf16x8 __attribute__((ext_vector_type(8)));
typedef float f32x4 __attribute__((ext_vector_type(4)));
typedef float f32x16 __attribute__((ext_vector_type(16)));

__device__ __forceinline__ void async16(const void* g, void* l) {
  __builtin_amdgcn_global_load_lds((const __attribute__((address_space(1))) void*)g,
                                   (__attribute__((address_space(3))) void*)l,
                                   16, 0, 0);
}

__device__ __forceinline__ f32x4 mfma16(bf16x8 a, bf16x8 b, f32x4 c) {
  return __builtin_amdgcn_mfma_f32_16x16x32_bf16(a, b, c, 0, 0, 0);
}
__device__ __forceinline__ f32x16 mfma32(bf16x8 a, bf16x8 b, f32x16 c) {
  return __builtin_amdgcn_mfma_f32_32x32x16_bf16(a, b, c, 0, 0, 0);
}
__device__ __forceinline__ uint32_t pkbf16(float lo, float hi) {
  uint32_t r;
  asm("v_cvt_pk_bf16_f32 %0, %1, %2" : "=v"(r) : "v"(lo), "v"(hi));
  return r;
}

// ---------------- fused fp32 -> bf16 conversion (all 5 tensors) ----------------
__global__ __launch_bounds__(256) void cvt_all(
    const float* __restrict__ i0, const float* __restrict__ i1,
    const float* __restrict__ i2, const float* __restrict__ i3,
    const float* __restrict__ i4, __bf16* __restrict__ o0,
    __bf16* __restrict__ o1, __bf16* __restrict__ o2, __bf16* __restrict__ o3,
    __bf16* __restrict__ o4) {
  int v = blockIdx.x * 256 + threadIdx.x;  // vec8 index; total 2359296
  const float* in;
  __bf16* out;
  int base;
  if (v < 1048576)      { in = i0; out = o0; base = 0; }
  else if (v < 1572864) { in = i1; out = o1; base = 1048576; }
  else if (v < 1703936) { in = i2; out = o2; base = 1572864; }
  else if (v < 1835008) { in = i3; out = o3; base = 1703936; }
  else                  { in = i4; out = o4; base = 1835008; }
  int i = (v - base) * 8;
  const float4* p = (const float4*)(in + i);
  float4 a = p[0], b = p[1];
  bf16x8 o;
  o[0] = (__bf16)a.x; o[1] = (__bf16)a.y; o[2] = (__bf16)a.z; o[3] = (__bf16)a.w;
  o[4] = (__bf16)b.x; o[5] = (__bf16)b.y; o[6] = (__bf16)b.z; o[7] = (__bf16)b.w;
  *(bf16x8*)(out + i) = o;
}

// ---------------- GEMM: C[m,n] = sum_k A[m,k]*B[n,k], 3-way N-routed ----------------
// VSEG2: the third segment's output is written in key-group-major Vt layout
// (fuses the former transpose_v kernel into the epilogue).
template <bool F32OUT, bool VSEG2>
__global__ __launch_bounds__(256) void gemm_bt(const __bf16* __restrict__ A,
                                               const __bf16* __restrict__ B0,
                                               const __bf16* __restrict__ B1,
                                               const __bf16* __restrict__ B2,
                                               void* __restrict__ C0,
                                               void* __restrict__ C1,
                                               void* __restrict__ C2,
                                               int Ntot, int Ns1, int Ns2, int K) {
  int nbn = Ntot >> 7;
  int nwg = gridDim.x;
  int bid = blockIdx.x;
  int bx = (bid & 7) * (nwg >> 3) + (bid >> 3);  // XCD swizzle (nwg % 8 == 0)
  int m0 = (bx / nbn) << 7;
  int n0g = (bx % nbn) << 7;
  const __bf16* B;
  void* C;
  int n0, Nc;
  bool seg2 = false;
  if (n0g < Ns1)      { B = B0; C = C0; n0 = n0g;       Nc = Ns1; }
  else if (n0g < Ns2) { B = B1; C = C1; n0 = n0g - Ns1; Nc = Ns2 - Ns1; }
  else                { B = B2; C = C2; n0 = n0g - Ns2; Nc = Ntot - Ns2; seg2 = true; }

  __shared__ __align__(16) uint8_t As[16384]; // [128][64] bf16, XOR-swizzled
  __shared__ __align__(16) uint8_t Bs[16384];

  int t = threadIdx.x, lane = t & 63, w = t >> 6;
  int wr = w >> 1, wc = w & 1;
  f32x4 acc[4][4] = {};

  for (int k0 = 0; k0 < K; k0 += 64) {
#pragma unroll
    for (int i = 0; i < 4; ++i) {
      int c = (i << 8) + t;
      int row = c >> 3;
      int colb = ((c & 7) << 4) ^ ((row & 7) << 4);
      async16((const uint8_t*)(A + (size_t)(m0 + row) * K + k0) + colb, As + c * 16);
      async16((const uint8_t*)(B + (size_t)(n0 + row) * K + k0) + colb, Bs + c * 16);
    }
    __syncthreads();
#pragma unroll
    for (int ks = 0; ks < 2; ++ks) {
      bf16x8 af[4], bfr[4];
#pragma unroll
      for (int m = 0; m < 4; ++m) {
        int row = wr * 64 + m * 16 + (lane & 15);
        int colb = ((ks << 6) + ((lane >> 4) << 4)) ^ ((row & 7) << 4);
        af[m] = *(const bf16x8*)(As + row * 128 + colb);
      }
#pragma unroll
      for (int n = 0; n < 4; ++n) {
        int row = wc * 64 + n * 16 + (lane & 15);
        int colb = ((ks << 6) + ((lane >> 4) << 4)) ^ ((row & 7) << 4);
        bfr[n] = *(const bf16x8*)(Bs + row * 128 + colb);
      }
      __builtin_amdgcn_s_setprio(1);
#pragma unroll
      for (int m = 0; m < 4; ++m)
#pragma unroll
        for (int n = 0; n < 4; ++n)
          acc[m][n] = mfma16(af[m], bfr[n], acc[m][n]);
      __builtin_amdgcn_s_setprio(0);
    }
    __syncthreads();
  }
#pragma unroll
  for (int m = 0; m < 4; ++m)
#pragma unroll
    for (int n = 0; n < 4; ++n)
#pragma unroll
      for (int j = 0; j < 4; ++j) {
        int mg = m0 + wr * 64 + m * 16 + ((lane >> 4) << 2) + j;
        int ng = n0 + wc * 64 + n * 16 + (lane & 15);
        float v = acc[m][n][j];
        if (VSEG2 && seg2) {
          // V output -> key-group-major Vt tiles:
          // Vt[((b*4+kvh)*32 + s/64)*8192 + ((s>>2)&15)*512 + d*4 + (s&3)]
          int bb = mg >> 11, s = mg & 2047;
          size_t vidx = ((size_t)((bb << 2) + (ng >> 7)) * 32 + (s >> 6)) * 8192 +
                        (size_t)((s >> 2) & 15) * 512 + (size_t)(ng & 127) * 4 +
                        (s & 3);
          ((__bf16*)C)[vidx] = (__bf16)v;
        } else if (F32OUT) {
          ((float*)C)[(size_t)mg * Nc + ng] = v;
        } else {
          ((__bf16*)C)[(size_t)mg * Nc + ng] = (__bf16)v;
        }
      }
}

// ---------------- causal GQA flash attention, 32x32 swapped-QK^T ----------------
// 4 waves x 32 q-rows (QBLK=128), KVBLK=64, in-register softmax (lane owns q=lane&31).
// 2-deep pipeline: QK^T(kt+1) [MFMA] overlaps softmax(kt) [VALU]. K staged 2 ahead
// into the same double buffer (slot kt&1 is dead at iter kt); V staged 1 ahead.
__global__ __launch_bounds__(256, 2) void attn(const __bf16* __restrict__ Q,
                                               const __bf16* __restrict__ Kx,
                                               const __bf16* __restrict__ Vt,
                                               __bf16* __restrict__ Ctx) {
  int bid0 = blockIdx.x;
  int bid = ((bid0 & 7) << 6) | (bid0 >> 3);  // XCD swizzle: 512 blocks, 64/XCD
  int qt = 15 - (bid & 15);
  int h = (bid >> 4) & 15;
  int b = bid >> 8;
  int kvh = h >> 2;
  int q0 = qt << 7;
  int t = threadIdx.x, lane = t & 63, w = t >> 6;
  int qr = lane & 31;   // own q-row within wave
  int hi = lane >> 5;
  int qwb = q0 + (w << 5);

  __shared__ __align__(16) uint8_t Ks[2][16384];  // [64 key][128 d] bf16, swizzled
  __shared__ __align__(16) uint8_t Vs[2][16384];  // [16 g][128 d][4 key] bf16, linear

  const __bf16* kbase = Kx + (size_t)b * S_LEN * 512 + kvh * HDK;
  const __bf16* vbase = Vt + (size_t)(b * NKVH + kvh) * 32 * 8192;

  auto stageK = [&](int kt, int slot) {
#pragma unroll
    for (int i = 0; i < 4; ++i) {
      int c = (i << 8) + t;
      int krow = c >> 4;
      int kcolb = ((c & 15) << 4) ^ ((krow & 7) << 4);
      async16((const uint8_t*)(kbase + (size_t)((kt << 6) + krow) * 512) + kcolb,
              Ks[slot] + c * 16);
    }
  };
  auto stageV = [&](int kt, int slot) {
#pragma unroll
    for (int i = 0; i < 4; ++i) {
      int c = (i << 8) + t;
      async16((const uint8_t*)(vbase + (size_t)kt * 8192) + c * 16,
              Vs[slot] + c * 16);
    }
  };

  int NT = (qt << 1) + 2;  // always even
  stageK(0, 0);
  stageV(0, 0);
  stageK(1, 1);

  // Q fragments: lane holds Q[q = qwb+qr][d = dk*16 + hi*8 + j]
  bf16x8 qf[8];
  {
    const __bf16* qrow = Q + (size_t)(b * S_LEN + qwb + qr) * DMODEL + h * HDK + hi * 8;
#pragma unroll
    for (int dk = 0; dk < 8; ++dk) qf[dk] = *(const bf16x8*)(qrow + dk * 16);
  }
  __syncthreads();  // stage(K0,V0,K1) drained

  const float NEG = -3.0e38f;
  const float SC = 0.08838834764831845f;  // 1/sqrt(128)
  const f32x16 vzero = {};
  float m_run = NEG, l_run = 0.f;         // l_run: own-half partial until epilogue
  f32x16 acc[4] = {};  // O[q][d], 4 d-tiles of 32

  // QK^T for a tile into (n0,n1), masked. keys row=(r&3)+8*(r>>2)+4*hi, col q=qr.
  auto qk = [&](int kt, f32x16& n0, f32x16& n1) {
    const uint8_t* ks = Ks[kt & 1];
    n0 = vzero; n1 = vzero;
    int swz = (qr & 7) << 4;
    __builtin_amdgcn_s_setprio(1);
#pragma unroll
    for (int dk = 0; dk < 8; ++dk) {
      int cb = (dk << 5) + (hi << 4);
      bf16x8 kf0 = *(const bf16x8*)(ks + qr * 256 + (cb ^ swz));
      n0 = mfma32(kf0, qf[dk], n0);
      bf16x8 kf1 = *(const bf16x8*)(ks + (32 + qr) * 256 + (cb ^ swz));
      n1 = mfma32(kf1, qf[dk], n1);
    }
    __builtin_amdgcn_s_setprio(0);
    int k0 = kt << 6;
    if (k0 + 63 > qwb) {  // causal mask (diagonal-adjacent tiles only)
#pragma unroll
      for (int r = 0; r < 16; ++r) {
        int kl = (r & 3) + ((r >> 2) << 3) + (hi << 2);
        n0[r] = (k0 + kl > qwb + qr) ? NEG : n0[r];
        n1[r] = (k0 + 32 + kl > qwb + qr) ? NEG : n1[r];
      }
    }
  };

  // softmax + PV for tile kt from score regs (c0,c1)
  auto smpv = [&](int kt, f32x16& c0, f32x16& c1) {
    // row max: explicit binary tree (depth 5) + one cross-half merge
    float tm[16];
#pragma unroll
    for (int r = 0; r < 16; ++r) tm[r] = fmaxf(c0[r], c1[r]);
#pragma unroll
    for (int s = 8; s > 0; s >>= 1)
#pragma unroll
      for (int r = 0; r < s; ++r) tm[r] = fmaxf(tm[r], tm[r + s]);
    float mx = fmaxf(tm[0], __shfl_xor(tm[0], 32, 64));

    // defer-max: rescale only when max grows by >8/SC in raw score units
    if (__any(mx > m_run + 90.52f)) {
      float mn = fmaxf(m_run, mx);
      float al = __expf((m_run - mn) * SC);
      l_run *= al;
      m_run = mn;
#pragma unroll
      for (int i = 0; i < 16; ++i) {
        float alr = __shfl(al, (i & 3) + ((i >> 2) << 3) + (hi << 2), 64);
        acc[0][i] *= alr; acc[1][i] *= alr; acc[2][i] *= alr; acc[3][i] *= alr;
      }
    }

    float mSC = m_run * SC;
    float p0[16], p1[16];
#pragma unroll
    for (int r = 0; r < 16; ++r) p0[r] = __expf(fmaf(c0[r], SC, -mSC));
#pragma unroll
    for (int r = 0; r < 16; ++r) p1[r] = __expf(fmaf(c1[r], SC, -mSC));
    // row sum: binary tree; cross-half merge deferred to epilogue (additive)
    float ts[16];
#pragma unroll
    for (int r = 0; r < 16; ++r) ts[r] = p0[r] + p1[r];
#pragma unroll
    for (int s = 8; s > 0; s >>= 1)
#pragma unroll
      for (int r = 0; r < s; ++r) ts[r] += ts[r + s];
    l_run += ts[0];

    // zero-shuffle A-fragments: pi(hi*8+j) = (j&3)+8*(j>>2)+4*hi matches the
    // QK^T C/D key ownership -> own p regs pack directly into pa[kc].
    bf16x8 pa[4];
    {
      union { bf16x8 v; uint32_t u[4]; } t0, t1, t2, t3;
#pragma unroll
      for (int i = 0; i < 4; ++i) {
        t0.u[i] = pkbf16(p0[2 * i], p0[2 * i + 1]);
        t1.u[i] = pkbf16(p0[8 + 2 * i], p0[9 + 2 * i]);
        t2.u[i] = pkbf16(p1[2 * i], p1[2 * i + 1]);
        t3.u[i] = pkbf16(p1[8 + 2 * i], p1[9 + 2 * i]);
      }
      pa[0] = t0.v; pa[1] = t1.v; pa[2] = t2.v; pa[3] = t3.v;
    }

    // O += P V : B-fragment = V keys {16kc+4hi..+3} (g0) and {16kc+8+4hi..+3} (g1)
    // at d-row; key-group-major layout makes both 8B reads bank-minimal.
    const uint8_t* vs = Vs[kt & 1];
    __builtin_amdgcn_s_setprio(1);
#pragma unroll
    for (int dt = 0; dt < 4; ++dt) {
      int row = (dt << 5) + qr;  // d index 0..127
#pragma unroll
      for (int kc = 0; kc < 4; ++kc) {
        int g0 = (kc << 2) + hi;
        union { bf16x8 v; uint64_t q[2]; } vfu;
        vfu.q[0] = *(const uint64_t*)(vs + (g0 << 10) + (row << 3));
        vfu.q[1] = *(const uint64_t*)(vs + ((g0 + 2) << 10) + (row << 3));
        acc[dt] = mfma32(pa[kc], vfu.v, acc[dt]);
      }
    }
    __builtin_amdgcn_s_setprio(0);
  };

  // pipelined iteration: stage(kt+2/K, kt+1/V); QK(kt+1) || softmax(kt); PV(kt)
  auto body = [&](int kt, f32x16& c0, f32x16& c1, f32x16& n0, f32x16& n1) {
    if (kt + 2 < NT) stageK(kt + 2, kt & 1);          // slot kt&1 dead since iter kt-1
    if (kt + 1 < NT) stageV(kt + 1, (kt + 1) & 1);    // slot free since iter kt-1
    if (kt + 1 < NT && ((kt + 1) << 6) <= qwb + 31) qk(kt + 1, n0, n1);
    if ((kt << 6) <= qwb + 31) smpv(kt, c0, c1);
    __syncthreads();  // drains stages; releases consumed slots
  };

  f32x16 sA0, sA1, sB0, sB1;
  qk(0, sA0, sA1);   // tile 0 never fully masked
  __syncthreads();   // all waves done reading Ks[0] before iter-0 overwrites it

  for (int kt = 0; kt < NT; kt += 2) {
    body(kt, sA0, sA1, sB0, sB1);
    body(kt + 1, sB0, sB1, sA0, sA1);
  }

  // epilogue: merge l halves once, normalize by per-row l, write out
  l_run += __shfl_xor(l_run, 32, 64);
#pragma unroll
  for (int i = 0; i < 16; ++i) {
    int rm = (i & 3) + ((i >> 2) << 3) + (hi << 2);
    float lr = __shfl(l_run, rm, 64);
    float inv = 1.0f / lr;
    size_t rowoff = (size_t)(b * S_LEN + qwb + rm) * DMODEL + h * HDK + qr;
#pragma unroll
    for (int dt = 0; dt < 4; ++dt)
      Ctx[rowoff + (dt << 5)] = (__bf16)(acc[dt][i] * inv);
  }
}

// ---------------- launch ----------------
extern "C" void kernel_launch(void* const* d_in, const int* in_sizes, int n_in,
                              void* d_out, int out_size, void* d_ws, size_t ws_size,
                              hipStream_t stream) {
  const float* x  = (const float*)d_in[0];
  const float* Wq = (const float*)d_in[1];
  const float* Wk = (const float*)d_in[2];
  const float* Wv = (const float*)d_in[3];
  const float* Wo = (const float*)d_in[4];
  float* out = (float*)d_out;

  const size_t MB = 1024 * 1024;
  uint8_t* ws = (uint8_t*)d_ws;
  __bf16* xb  = (__bf16*)(ws + 0 * MB);   // 16 MB  (4096 x 2048)
  __bf16* Wqb = (__bf16*)(ws + 16 * MB);  //  8 MB  (2048 x 2048)
  __bf16* Wkb = (__bf16*)(ws + 24 * MB);  //  2 MB  (512 x 2048)
  __bf16* Wvb = (__bf16*)(ws + 26 * MB);  //  2 MB
  __bf16* Wob = (__bf16*)(ws + 28 * MB);  //  8 MB
  __bf16* Qb  = (__bf16*)(ws + 36 * MB);  // 16 MB  (4096 x 2048)
  __bf16* Kb  = (__bf16*)(ws + 52 * MB);  //  4 MB  (4096 x 512)
  __bf16* Vtb = (__bf16*)(ws + 60 * MB);  //  4 MB  (key-group-major tiles)
  __bf16* Ctx = (__bf16*)(ws + 64 * MB);  // 16 MB  (4096 x 2048)

  // fused conversion: 18.9M elems / 8 per thread / 256 per block = 9216 blocks
  cvt_all<<<9216, 256, 0, stream>>>(x, Wq, Wk, Wv, Wo, xb, Wqb, Wkb, Wvb, Wob);

  // fused QKV projection: (4096x2048) x [Wq;Wk;Wv]^T, N = 2048+512+512.
  // V segment's epilogue writes key-group-major Vt directly (transpose fused).
  gemm_bt<false, true><<<(4096 / 128) * (3072 / 128), 256, 0, stream>>>(
      xb, Wqb, Wkb, Wvb, (void*)Qb, (void*)Kb, (void*)Vtb, 3072, 2048, 2560, 2048);

  attn<<<512, 256, 0, stream>>>(Qb, Kb, Vtb, Ctx);

  // output projection: (4096x2048) x (2048x2048)^T -> fp32
  gemm_bt<true, false><<<(4096 / 128) * (2048 / 128), 256, 0, stream>>>(
      Ctx, Wob, Wob, Wob, (void*)out, (void*)out, (void*)out, 2048, 2048, 2048, 2048);
}

// Round 15
// 191.792 us; speedup vs baseline: 1.0731x; 1.0731x over previous
//
#include <hip/hip_runtime.h>
#include <stdint.h>

#define S_LEN 2048
#define DMODEL 2048
#define NQH 16
#define NKVH 4
#define HDK 128

typedef __bf16 bf16x8 __attribute__((ext_vector_type(8)));
typedef float f32x4 __attribute__((ext_vector_type(4)));
typedef float f32x16 __attribute__((ext_vector_type(16)));

__device__ __forceinline__ void async16(const void* g, void* l) {
  __builtin_amdgcn_global_load_lds((const __attribute__((address_space(1))) void*)g,
                                   (__attribute__((address_space(3))) void*)l,
                                   16, 0, 0);
}

__device__ __forceinline__ f32x4 mfma16(bf16x8 a, bf16x8 b, f32x4 c) {
  return __builtin_amdgcn_mfma_f32_16x16x32_bf16(a, b, c, 0, 0, 0);
}
__device__ __forceinline__ f32x16 mfma32(bf16x8 a, bf16x8 b, f32x16 c) {
  return __builtin_amdgcn_mfma_f32_32x32x16_bf16(a, b, c, 0, 0, 0);
}
__device__ __forceinline__ uint32_t pkbf16(float lo, float hi) {
  uint32_t r;
  asm("v_cvt_pk_bf16_f32 %0, %1, %2" : "=v"(r) : "v"(lo), "v"(hi));
  return r;
}

// ---------------- fused fp32 -> bf16 conversion (all 5 tensors) ----------------
__global__ __launch_bounds__(256) void cvt_all(
    const float* __restrict__ i0, const float* __restrict__ i1,
    const float* __restrict__ i2, const float* __restrict__ i3,
    const float* __restrict__ i4, __bf16* __restrict__ o0,
    __bf16* __restrict__ o1, __bf16* __restrict__ o2, __bf16* __restrict__ o3,
    __bf16* __restrict__ o4) {
  int v = blockIdx.x * 256 + threadIdx.x;  // vec8 index; total 2359296
  const float* in;
  __bf16* out;
  int base;
  if (v < 1048576)      { in = i0; out = o0; base = 0; }
  else if (v < 1572864) { in = i1; out = o1; base = 1048576; }
  else if (v < 1703936) { in = i2; out = o2; base = 1572864; }
  else if (v < 1835008) { in = i3; out = o3; base = 1703936; }
  else                  { in = i4; out = o4; base = 1835008; }
  int i = (v - base) * 8;
  const float4* p = (const float4*)(in + i);
  float4 a = p[0], b = p[1];
  bf16x8 o;
  o[0] = (__bf16)a.x; o[1] = (__bf16)a.y; o[2] = (__bf16)a.z; o[3] = (__bf16)a.w;
  o[4] = (__bf16)b.x; o[5] = (__bf16)b.y; o[6] = (__bf16)b.z; o[7] = (__bf16)b.w;
  *(bf16x8*)(out + i) = o;
}

// ---------------- GEMM: C[m,n] = sum_k A[m,k]*B[n,k], 3-way N-routed ----------------
// VSEG2: the third segment's output is written in key-group-major Vt layout
// (fuses the former transpose_v kernel into the epilogue).
template <bool F32OUT, bool VSEG2>
__global__ __launch_bounds__(256) void gemm_bt(const __bf16* __restrict__ A,
                                               const __bf16* __restrict__ B0,
                                               const __bf16* __restrict__ B1,
                                               const __bf16* __restrict__ B2,
                                               void* __restrict__ C0,
                                               void* __restrict__ C1,
                                               void* __restrict__ C2,
                                               int Ntot, int Ns1, int Ns2, int K) {
  int nbn = Ntot >> 7;
  int nwg = gridDim.x;
  int bid = blockIdx.x;
  int bx = (bid & 7) * (nwg >> 3) + (bid >> 3);  // XCD swizzle (nwg % 8 == 0)
  int m0 = (bx / nbn) << 7;
  int n0g = (bx % nbn) << 7;
  const __bf16* B;
  void* C;
  int n0, Nc;
  bool seg2 = false;
  if (n0g < Ns1)      { B = B0; C = C0; n0 = n0g;       Nc = Ns1; }
  else if (n0g < Ns2) { B = B1; C = C1; n0 = n0g - Ns1; Nc = Ns2 - Ns1; }
  else                { B = B2; C = C2; n0 = n0g - Ns2; Nc = Ntot - Ns2; seg2 = true; }

  __shared__ __align__(16) uint8_t As[16384]; // [128][64] bf16, XOR-swizzled
  __shared__ __align__(16) uint8_t Bs[16384];

  int t = threadIdx.x, lane = t & 63, w = t >> 6;
  int wr = w >> 1, wc = w & 1;
  f32x4 acc[4][4] = {};

  for (int k0 = 0; k0 < K; k0 += 64) {
#pragma unroll
    for (int i = 0; i < 4; ++i) {
      int c = (i << 8) + t;
      int row = c >> 3;
      int colb = ((c & 7) << 4) ^ ((row & 7) << 4);
      async16((const uint8_t*)(A + (size_t)(m0 + row) * K + k0) + colb, As + c * 16);
      async16((const uint8_t*)(B + (size_t)(n0 + row) * K + k0) + colb, Bs + c * 16);
    }
    __syncthreads();
#pragma unroll
    for (int ks = 0; ks < 2; ++ks) {
      bf16x8 af[4], bfr[4];
#pragma unroll
      for (int m = 0; m < 4; ++m) {
        int row = wr * 64 + m * 16 + (lane & 15);
        int colb = ((ks << 6) + ((lane >> 4) << 4)) ^ ((row & 7) << 4);
        af[m] = *(const bf16x8*)(As + row * 128 + colb);
      }
#pragma unroll
      for (int n = 0; n < 4; ++n) {
        int row = wc * 64 + n * 16 + (lane & 15);
        int colb = ((ks << 6) + ((lane >> 4) << 4)) ^ ((row & 7) << 4);
        bfr[n] = *(const bf16x8*)(Bs + row * 128 + colb);
      }
      __builtin_amdgcn_s_setprio(1);
#pragma unroll
      for (int m = 0; m < 4; ++m)
#pragma unroll
        for (int n = 0; n < 4; ++n)
          acc[m][n] = mfma16(af[m], bfr[n], acc[m][n]);
      __builtin_amdgcn_s_setprio(0);
    }
    __syncthreads();
  }
#pragma unroll
  for (int m = 0; m < 4; ++m)
#pragma unroll
    for (int n = 0; n < 4; ++n)
#pragma unroll
      for (int j = 0; j < 4; ++j) {
        int mg = m0 + wr * 64 + m * 16 + ((lane >> 4) << 2) + j;
        int ng = n0 + wc * 64 + n * 16 + (lane & 15);
        float v = acc[m][n][j];
        if (VSEG2 && seg2) {
          // V output -> key-group-major Vt tiles:
          // Vt[((b*4+kvh)*32 + s/64)*8192 + ((s>>2)&15)*512 + d*4 + (s&3)]
          int bb = mg >> 11, s = mg & 2047;
          size_t vidx = ((size_t)((bb << 2) + (ng >> 7)) * 32 + (s >> 6)) * 8192 +
                        (size_t)((s >> 2) & 15) * 512 + (size_t)(ng & 127) * 4 +
                        (s & 3);
          ((__bf16*)C)[vidx] = (__bf16)v;
        } else if (F32OUT) {
          ((float*)C)[(size_t)mg * Nc + ng] = v;
        } else {
          ((__bf16*)C)[(size_t)mg * Nc + ng] = (__bf16)v;
        }
      }
}

// ---------------- causal GQA flash attention, 32x32 swapped-QK^T ----------------
// 4 waves x 32 q-rows (QBLK=128), KVBLK=64, in-register softmax (lane owns q=lane&31).
// Zero-shuffle PV (pi = QK^T C/D key ownership); V in key-group-major LDS tiles so
// the two 8B B-fragment reads are bank-minimal; V staging is a pure linear copy.
__global__ __launch_bounds__(256, 2) void attn(const __bf16* __restrict__ Q,
                                               const __bf16* __restrict__ Kx,
                                               const __bf16* __restrict__ Vt,
                                               __bf16* __restrict__ Ctx) {
  int bid0 = blockIdx.x;
  int bid = ((bid0 & 7) << 6) | (bid0 >> 3);  // XCD swizzle: 512 blocks, 64/XCD
  int qt = 15 - (bid & 15);
  int h = (bid >> 4) & 15;
  int b = bid >> 8;
  int kvh = h >> 2;
  int q0 = qt << 7;
  int t = threadIdx.x, lane = t & 63, w = t >> 6;
  int qr = lane & 31;   // own q-row within wave
  int hi = lane >> 5;
  int qwb = q0 + (w << 5);

  __shared__ __align__(16) uint8_t Ks[2][16384];  // [64 key][128 d] bf16, swizzled
  __shared__ __align__(16) uint8_t Vs[2][16384];  // [16 g][128 d][4 key] bf16, linear

  const __bf16* kbase = Kx + (size_t)b * S_LEN * 512 + kvh * HDK;
  const __bf16* vbase = Vt + (size_t)(b * NKVH + kvh) * 32 * 8192;

  auto stage = [&](int kt, int bufi) {
#pragma unroll
    for (int i = 0; i < 4; ++i) {
      int c = (i << 8) + t;
      int krow = c >> 4;
      int kcolb = ((c & 15) << 4) ^ ((krow & 7) << 4);
      async16((const uint8_t*)(kbase + (size_t)((kt << 6) + krow) * 512) + kcolb,
              Ks[bufi] + c * 16);
      async16((const uint8_t*)(vbase + (size_t)kt * 8192) + c * 16,
              Vs[bufi] + c * 16);
    }
  };

  int NT = (qt << 1) + 2;
  stage(0, 0);

  // Q fragments: lane holds Q[q = qwb+qr][d = dk*16 + hi*8 + j]
  bf16x8 qf[8];
  {
    const __bf16* qrow = Q + (size_t)(b * S_LEN + qwb + qr) * DMODEL + h * HDK + hi * 8;
#pragma unroll
    for (int dk = 0; dk < 8; ++dk) qf[dk] = *(const bf16x8*)(qrow + dk * 16);
  }
  __syncthreads();  // stage(0) drained

  const float NEG = -3.0e38f;
  const float SC = 0.08838834764831845f;  // 1/sqrt(128)
  float m_run = NEG, l_run = 0.f;         // l_run: own-half partial until epilogue
  f32x16 acc[4] = {};  // O[q][d], 4 d-tiles of 32

  for (int kt = 0; kt < NT; ++kt) {
    int cur = kt & 1;
    if (kt + 1 < NT) stage(kt + 1, cur ^ 1);
    int k0 = kt << 6;
    if (k0 <= qwb + 31) {  // wave-uniform skip of fully-masked tiles
      const uint8_t* ks = Ks[cur];
      const uint8_t* vs = Vs[cur];

      // S^T = K Q^T : D[key][q], col=q=lane&31, row=(r&3)+8*(r>>2)+4*hi
      f32x16 st0 = {}, st1 = {};
      __builtin_amdgcn_s_setprio(1);
#pragma unroll
      for (int dk = 0; dk < 8; ++dk) {
        int cb = (dk << 5) + (hi << 4);
        int swz = (qr & 7) << 4;
        bf16x8 kf0 = *(const bf16x8*)(ks + qr * 256 + (cb ^ swz));
        st0 = mfma32(kf0, qf[dk], st0);
        bf16x8 kf1 = *(const bf16x8*)(ks + (32 + qr) * 256 + (cb ^ swz));
        st1 = mfma32(kf1, qf[dk], st1);
      }
      __builtin_amdgcn_s_setprio(0);

      // causal mask (diagonal-adjacent tiles only)
      if (k0 + 63 > qwb) {
#pragma unroll
        for (int r = 0; r < 16; ++r) {
          int kl = (r & 3) + ((r >> 2) << 3) + (hi << 2);
          st0[r] = (k0 + kl > qwb + qr) ? NEG : st0[r];
          st1[r] = (k0 + 32 + kl > qwb + qr) ? NEG : st1[r];
        }
      }

      // row max: explicit binary tree (depth 5) + one cross-half merge
      float tm[16];
#pragma unroll
      for (int r = 0; r < 16; ++r) tm[r] = fmaxf(st0[r], st1[r]);
#pragma unroll
      for (int s = 8; s > 0; s >>= 1)
#pragma unroll
        for (int r = 0; r < s; ++r) tm[r] = fmaxf(tm[r], tm[r + s]);
      float mx = fmaxf(tm[0], __shfl_xor(tm[0], 32, 64));

      // defer-max: rescale only when max grows by >8/SC in raw score units
      if (__any(mx > m_run + 90.52f)) {
        float mn = fmaxf(m_run, mx);
        float al = __expf((m_run - mn) * SC);
        l_run *= al;
        m_run = mn;
#pragma unroll
        for (int i = 0; i < 16; ++i) {
          float alr = __shfl(al, (i & 3) + ((i >> 2) << 3) + (hi << 2), 64);
          acc[0][i] *= alr; acc[1][i] *= alr; acc[2][i] *= alr; acc[3][i] *= alr;
        }
      }

      float mSC = m_run * SC;
      float p0[16], p1[16];
#pragma unroll
      for (int r = 0; r < 16; ++r) p0[r] = __expf(fmaf(st0[r], SC, -mSC));
#pragma unroll
      for (int r = 0; r < 16; ++r) p1[r] = __expf(fmaf(st1[r], SC, -mSC));
      // row sum: binary tree; cross-half merge deferred to epilogue (additive)
      float ts[16];
#pragma unroll
      for (int r = 0; r < 16; ++r) ts[r] = p0[r] + p1[r];
#pragma unroll
      for (int s = 8; s > 0; s >>= 1)
#pragma unroll
        for (int r = 0; r < s; ++r) ts[r] += ts[r + s];
      l_run += ts[0];

      // zero-shuffle A-fragments: pi(hi*8+j) = (j&3)+8*(j>>2)+4*hi matches the
      // QK^T C/D key ownership -> own p regs pack directly into pa[kc].
      bf16x8 pa[4];
      {
        union { bf16x8 v; uint32_t u[4]; } t0, t1, t2, t3;
#pragma unroll
        for (int i = 0; i < 4; ++i) {
          t0.u[i] = pkbf16(p0[2 * i], p0[2 * i + 1]);
          t1.u[i] = pkbf16(p0[8 + 2 * i], p0[9 + 2 * i]);
          t2.u[i] = pkbf16(p1[2 * i], p1[2 * i + 1]);
          t3.u[i] = pkbf16(p1[8 + 2 * i], p1[9 + 2 * i]);
        }
        pa[0] = t0.v; pa[1] = t1.v; pa[2] = t2.v; pa[3] = t3.v;
      }

      // O += P V : B-fragment = V keys {16kc+4hi..+3} (g0) and {16kc+8+4hi..+3} (g1)
      // at d-row; key-group-major layout makes both 8B reads bank-minimal.
      __builtin_amdgcn_s_setprio(1);
#pragma unroll
      for (int dt = 0; dt < 4; ++dt) {
        int row = (dt << 5) + qr;  // d index 0..127
#pragma unroll
        for (int kc = 0; kc < 4; ++kc) {
          int g0 = (kc << 2) + hi;
          union { bf16x8 v; uint64_t q[2]; } vfu;
          vfu.q[0] = *(const uint64_t*)(vs + (g0 << 10) + (row << 3));
          vfu.q[1] = *(const uint64_t*)(vs + ((g0 + 2) << 10) + (row << 3));
          acc[dt] = mfma32(pa[kc], vfu.v, acc[dt]);
        }
      }
      __builtin_amdgcn_s_setprio(0);
    }
    __syncthreads();  // single barrier: drains next-tile stage, releases cur buf
  }

  // epilogue: merge l halves once, normalize by per-row l, write out
  l_run += __shfl_xor(l_run, 32, 64);
#pragma unroll
  for (int i = 0; i < 16; ++i) {
    int rm = (i & 3) + ((i >> 2) << 3) + (hi << 2);
    float lr = __shfl(l_run, rm, 64);
    float inv = 1.0f / lr;
    size_t rowoff = (size_t)(b * S_LEN + qwb + rm) * DMODEL + h * HDK + qr;
#pragma unroll
    for (int dt = 0; dt < 4; ++dt)
      Ctx[rowoff + (dt << 5)] = (__bf16)(acc[dt][i] * inv);
  }
}

// ---------------- launch ----------------
extern "C" void kernel_launch(void* const* d_in, const int* in_sizes, int n_in,
                              void* d_out, int out_size, void* d_ws, size_t ws_size,
                              hipStream_t stream) {
  const float* x  = (const float*)d_in[0];
  const float* Wq = (const float*)d_in[1];
  const float* Wk = (const float*)d_in[2];
  const float* Wv = (const float*)d_in[3];
  const float* Wo = (const float*)d_in[4];
  float* out = (float*)d_out;

  const size_t MB = 1024 * 1024;
  uint8_t* ws = (uint8_t*)d_ws;
  __bf16* xb  = (__bf16*)(ws + 0 * MB);   // 16 MB  (4096 x 2048)
  __bf16* Wqb = (__bf16*)(ws + 16 * MB);  //  8 MB  (2048 x 2048)
  __bf16* Wkb = (__bf16*)(ws + 24 * MB);  //  2 MB  (512 x 2048)
  __bf16* Wvb = (__bf16*)(ws + 26 * MB);  //  2 MB
  __bf16* Wob = (__bf16*)(ws + 28 * MB);  //  8 MB
  __bf16* Qb  = (__bf16*)(ws + 36 * MB);  // 16 MB  (4096 x 2048)
  __bf16* Kb  = (__bf16*)(ws + 52 * MB);  //  4 MB  (4096 x 512)
  __bf16* Vtb = (__bf16*)(ws + 60 * MB);  //  4 MB  (key-group-major tiles)
  __bf16* Ctx = (__bf16*)(ws + 64 * MB);  // 16 MB  (4096 x 2048)

  // fused conversion: 18.9M elems / 8 per thread / 256 per block = 9216 blocks
  cvt_all<<<9216, 256, 0, stream>>>(x, Wq, Wk, Wv, Wo, xb, Wqb, Wkb, Wvb, Wob);

  // fused QKV projection: (4096x2048) x [Wq;Wk;Wv]^T, N = 2048+512+512.
  // V segment's epilogue writes key-group-major Vt directly (transpose fused).
  gemm_bt<false, true><<<(4096 / 128) * (3072 / 128), 256, 0, stream>>>(
      xb, Wqb, Wkb, Wvb, (void*)Qb, (void*)Kb, (void*)Vtb, 3072, 2048, 2560, 2048);

  attn<<<512, 256, 0, stream>>>(Qb, Kb, Vtb, Ctx);

  // output projection: (4096x2048) x (2048x2048)^T -> fp32
  gemm_bt<true, false><<<(4096 / 128) * (2048 / 128), 256, 0, stream>>>(
      Ctx, Wob, Wob, Wob, (void*)out, (void*)out, (void*)out, 2048, 2048, 2048, 2048);
}